// Round 10
// baseline (323.609 us; speedup 1.0000x reference)
//
#include <hip/hip_runtime.h>

// ---------------------------------------------------------------------------
// DCGRU cell on MI355X — hop_v4: K-tile-contiguous packed A + counted ring.
// B=32, N=1024, C_IN=2, H=32, S=2, K=2, NUM_MAT=5, c_cat=34.
//
// ws (pathA): [Apk 128MB][H1 15MB][H2 15MB][ubuf 4MB]
// Apk: tile T = (mat*4 + mblk)*16 + kt  (mat = b*2+s), each tile 32 KB
//   contiguous; chunk c (16B) holds A[mblk*256 + (c>>3)][kt*64 + u*8..+8],
//   u = (c&7) ^ ((c>>3)&7)  — i.e. exactly the swizzled LDS image.
// H buffer: per b: 5 slots x 3 ct x [16 ch][1024 n] bf16; ch 34..47 zero pad.
// Output: d_out = (outputs, outputs), each 1,048,576 fp32.
//
// hop_v4: BM=256 (512 thr, 8 waves), BK=64, 3-buffer LDS ring, per step:
// WAIT vmcnt(5|4) -> s_barrier -> ISSUE(kt+2) -> COMPUTE(kt). A-tile loads are
// fully contiguous 32KB bursts; per-block kt phase stagger decorrelates blocks.
// ---------------------------------------------------------------------------

#define NN   1024
#define HB   245760
#define SUBT 16384
#define OUTCOPY 1048576
#define BUFSZ 38912   // 32768 (A) + 6144 (X)

typedef float  f32x4  __attribute__((ext_vector_type(4)));
typedef short  s16x4  __attribute__((ext_vector_type(4)));
typedef short  s16x8  __attribute__((ext_vector_type(8)));
typedef __bf16 bf16x8 __attribute__((ext_vector_type(8)));
typedef unsigned int u32x4 __attribute__((ext_vector_type(4)));

#define GAS __attribute__((address_space(1)))
#define LAS __attribute__((address_space(3)))

__device__ __forceinline__ unsigned short f32_bf16(float f) {
  unsigned int u = __float_as_uint(f);
  u += 0x7FFFu + ((u >> 16) & 1u);        // RNE
  return (unsigned short)(u >> 16);
}
__device__ __forceinline__ float bf16_f32(unsigned short h) {
  return __uint_as_float(((unsigned int)h) << 16);
}
__device__ __forceinline__ void gload_lds16(const unsigned short* g, void* l) {
  __builtin_amdgcn_global_load_lds((const GAS void*)g, (LAS void*)l, 16, 0, 0);
}

// ---------------------------------------------------------------------------
// cvt_pack: supports fp32 -> Apk (K-tile-contiguous swizzled bf16 image).
// Writes perfectly coalesced (16B/lane sequential); reads are 256B windows
// per 8-lane row-group with high (mat,mblk,kt) diversity across blocks.
// ---------------------------------------------------------------------------
__global__ __launch_bounds__(256)
void cvt_pack(const float* __restrict__ src, unsigned short* __restrict__ Apk) {
  int g0 = blockIdx.x * 256 + threadIdx.x;
#pragma unroll 1
  for (int g = g0; g < 8388608; g += 524288) {
    int c    = g & 2047;
    int kt   = (g >> 11) & 15;
    int mblk = (g >> 15) & 3;
    int mat  = g >> 17;
    int r = c >> 3, cs = c & 7;
    int u = cs ^ (r & 7);
    const float* p = src + ((size_t)mat << 20) + (size_t)(mblk * 256 + r) * 1024
                         + kt * 64 + u * 8;
    f32x4 v0 = *(const f32x4*)p;
    f32x4 v1 = *(const f32x4*)(p + 4);
    s16x8 o;
    o[0] = (short)f32_bf16(v0[0]); o[1] = (short)f32_bf16(v0[1]);
    o[2] = (short)f32_bf16(v0[2]); o[3] = (short)f32_bf16(v0[3]);
    o[4] = (short)f32_bf16(v1[0]); o[5] = (short)f32_bf16(v1[1]);
    o[6] = (short)f32_bf16(v1[2]); o[7] = (short)f32_bf16(v1[3]);
    *(s16x8*)(Apk + (size_t)g * 8) = o;
  }
}

// ---------------------------------------------------------------------------
// pack x1 = [inputs, states] into H1 slot 0 (XT layout)
// ---------------------------------------------------------------------------
__global__ __launch_bounds__(256)
void pack_x1(const float* __restrict__ inputs, const float* __restrict__ states,
             unsigned short* __restrict__ H1) {
  int gid = blockIdx.x * 256 + threadIdx.x;   // 0..32767
  int b = gid >> 10, n = gid & 1023;
  unsigned short* xb = H1 + (size_t)b * HB;
  xb[0 * NN + n] = f32_bf16(inputs[gid * 2 + 0]);
  xb[1 * NN + n] = f32_bf16(inputs[gid * 2 + 1]);
#pragma unroll
  for (int o = 0; o < 32; ++o) {
    int ch = 2 + o;
    xb[(ch >> 4) * SUBT + (ch & 15) * NN + n] = f32_bf16(states[gid * 32 + o]);
  }
#pragma unroll
  for (int ch = 34; ch < 48; ++ch)
    xb[2 * SUBT + (ch & 15) * NN + n] = 0;
}

// ---------------------------------------------------------------------------
// hop_v4
// ---------------------------------------------------------------------------
__global__ __launch_bounds__(512, 2)
void hop_v4(const unsigned short* __restrict__ Apk,
            const unsigned short* __restrict__ Hin,
            unsigned short* __restrict__ Hout,
            int si0, int si1, int so0, int so1) {
  __shared__ u32x4 ldsv[3 * 2432];   // 3 x 38912 B
  char* lds = (char*)ldsv;

  const int tid  = threadIdx.x;
  const int wave = tid >> 6, lane = tid & 63;
  const int l15  = lane & 15,  l4  = lane >> 4;
  const int mblk = blockIdx.x, b = blockIdx.y, s = blockIdx.z;
  const int mat  = b * 2 + s;
  const int phase = (b + s * 8 + mblk * 4) & 15;   // k-phase stagger
  const int slot_in  = s ? si1 : si0;
  const int slot_out = s ? so1 : so0;

  const unsigned short* Xb = Hin  + (size_t)b * HB + (size_t)slot_in  * 3 * SUBT;
  unsigned short*       Yb = Hout + (size_t)b * HB + (size_t)slot_out * 3 * SUBT;
  const size_t tbase = (size_t)(mat * 4 + mblk) * 16 * 16384;  // ushort offset, kt=0

  // issue one K-tile: A = 4 contiguous 1KB/instr bursts (32KB), X = 6KB strided
  auto ISSUE = [&](int ktl, char* base) {
    const int ktp = (ktl + phase) & 15;
    const unsigned short* At = Apk + tbase + (size_t)ktp * 16384;
    const int kb0 = ktp << 6;
#pragma unroll
    for (int i = 0; i < 4; ++i)
      gload_lds16(At + (i * 512 + tid) * 8, base + (i * 512 + wave * 64) * 16);
    if (tid < 384) {
      int ct = tid >> 7, rem = tid & 127, ch = rem >> 3, cs = rem & 7;
      gload_lds16(Xb + ct * SUBT + ch * NN + kb0 + ((cs ^ (ch & 7)) << 3),
                  base + 32768 + (wave * 64) * 16);
    }
  };

  f32x4 acc[2][3];
#pragma unroll
  for (int mt = 0; mt < 2; ++mt)
#pragma unroll
    for (int nt = 0; nt < 3; ++nt)
#pragma unroll
      for (int e = 0; e < 4; ++e) acc[mt][nt][e] = 0.f;

  const int swx = (l15 & 7) << 4;

  auto COMPUTE = [&](const char* bc) {
    const char* lXb = bc + 32768;
#pragma unroll
    for (int kb = 0; kb < 2; ++kb) {
      const int ko = kb * 64 + (l4 << 3);
      bf16x8 afr[2];
#pragma unroll
      for (int mt = 0; mt < 2; ++mt) {
        int row = wave * 32 + mt * 16 + l15;
        int sw  = (row & 7) << 4;
        s16x8 t;
        t.lo = *(const s16x4*)(bc + row * 128 + (ko ^ sw));
        t.hi = *(const s16x4*)(bc + row * 128 + ((ko + 32) ^ sw));
        afr[mt] = __builtin_bit_cast(bf16x8, t);
      }
#pragma unroll
      for (int nt = 0; nt < 3; ++nt) {
        const char* bp = lXb + (nt * 16 + l15) * 128;
        s16x8 t;
        t.lo = *(const s16x4*)(bp + (ko ^ swx));
        t.hi = *(const s16x4*)(bp + ((ko + 32) ^ swx));
        bf16x8 bfr = __builtin_bit_cast(bf16x8, t);
#pragma unroll
        for (int mt = 0; mt < 2; ++mt)
          acc[mt][nt] = __builtin_amdgcn_mfma_f32_16x16x32_bf16(afr[mt], bfr, acc[mt][nt], 0, 0, 0);
      }
    }
  };

#define WB_MAIN() do {                                                   \
    if (wave < 6) asm volatile("s_waitcnt vmcnt(5)" ::: "memory");       \
    else          asm volatile("s_waitcnt vmcnt(4)" ::: "memory");       \
    __builtin_amdgcn_s_barrier();                                        \
    __builtin_amdgcn_sched_barrier(0);                                   \
  } while (0)
#define WB_LAST() do {                                                   \
    asm volatile("s_waitcnt vmcnt(0)" ::: "memory");                     \
    __builtin_amdgcn_s_barrier();                                        \
    __builtin_amdgcn_sched_barrier(0);                                   \
  } while (0)

  char* bA = lds;               // compute buffer (tile kt)
  char* bB = lds + BUFSZ;       // in-flight (tile kt+1)
  char* bC = lds + 2 * BUFSZ;   // issue target (tile kt+2)

  ISSUE(0, bA);
  ISSUE(1, bB);

#pragma unroll 1
  for (int kt = 0; kt < 14; ++kt) {
    WB_MAIN();
    ISSUE(kt + 2, bC);
    COMPUTE(bA);
    char* t = bA; bA = bB; bB = bC; bC = t;
  }
  WB_MAIN();  COMPUTE(bA);      // kt=14
  bA = bB;
  WB_LAST();  COMPUTE(bA);      // kt=15

#undef WB_MAIN
#undef WB_LAST

  // epilogue: D layout col(n)=l15, row(m)=l4*4+reg
#pragma unroll
  for (int mt = 0; mt < 2; ++mt) {
    const int row0 = mblk * 256 + wave * 32 + mt * 16 + (l4 << 2);
#pragma unroll
    for (int nt = 0; nt < 3; ++nt) {
      int ch = nt * 16 + l15;
      s16x4 o;
      o.x = (short)f32_bf16(acc[mt][nt][0]);
      o.y = (short)f32_bf16(acc[mt][nt][1]);
      o.z = (short)f32_bf16(acc[mt][nt][2]);
      o.w = (short)f32_bf16(acc[mt][nt][3]);
      *(s16x4*)(Yb + (size_t)ch * NN + row0) = o;
    }
  }
}

// ---------------------------------------------------------------------------
// hop_slow fallback (fp32 A, reg-staged) — proven round-2 version
// ---------------------------------------------------------------------------
__global__ __launch_bounds__(256)
void hop_slow(const float* __restrict__ Af32,
              const unsigned short* __restrict__ Hin,
              unsigned short* __restrict__ Hout,
              int si0, int si1, int so0, int so1) {
  __shared__ u32x4 lA4[1024];
  __shared__ u32x4 lX4[384];
  const int tid  = threadIdx.x;
  const int wave = tid >> 6, lane = tid & 63;
  const int l15  = lane & 15,  l4  = lane >> 4;
  const int mblk = blockIdx.x, b = blockIdx.y, s = blockIdx.z;
  const int slot_in  = s ? si1 : si0;
  const int slot_out = s ? so1 : so0;
  const unsigned short* Xb = Hin  + (size_t)b * HB + (size_t)slot_in  * 3 * SUBT;
  unsigned short*       Yb = Hout + (size_t)b * HB + (size_t)slot_out * 3 * SUBT;
  const size_t arow0 = ((size_t)(b * 2 + s) * NN + (size_t)mblk * 128) * NN;
  f32x4 acc[2][3];
#pragma unroll
  for (int mt = 0; mt < 2; ++mt)
#pragma unroll
    for (int nt = 0; nt < 3; ++nt)
#pragma unroll
      for (int e = 0; e < 4; ++e) acc[mt][nt][e] = 0.f;
  char* lAb = (char*)lA4;
  char* lXb = (char*)lX4;
  for (int kt = 0; kt < 16; ++kt) {
    const int kb0 = kt * 64;
    __syncthreads();
#pragma unroll
    for (int i = 0; i < 8; ++i) {
      int q = i * 256 + tid;
      int r = q >> 4, c = q & 15;
      float4 v = *(const float4*)(Af32 + arow0 + (size_t)r * NN + kb0 + c * 4);
      s16x4 o;
      o.x = (short)f32_bf16(v.x); o.y = (short)f32_bf16(v.y);
      o.z = (short)f32_bf16(v.z); o.w = (short)f32_bf16(v.w);
      *(s16x4*)(lAb + r * 128 + ((c * 8) ^ ((r & 7) << 4))) = o;
    }
    {
      int q = tid;
      int ct = q >> 7, rem = q & 127, ch = rem >> 3, c = rem & 7;
      const u32x4* src = (const u32x4*)(Xb + ct * SUBT + ch * NN + kb0 + c * 8);
      *(u32x4*)(lXb + ct * 2048 + ch * 128 + ((c ^ (ch & 7)) << 4)) = *src;
      if (tid < 128) {
        q = 256 + tid;
        ct = q >> 7; rem = q & 127; ch = rem >> 3; c = rem & 7;
        src = (const u32x4*)(Xb + ct * SUBT + ch * NN + kb0 + c * 8);
        *(u32x4*)(lXb + ct * 2048 + ch * 128 + ((c ^ (ch & 7)) << 4)) = *src;
      }
    }
    __syncthreads();
#pragma unroll
    for (int kb = 0; kb < 2; ++kb) {
      const int ko = kb * 64 + (l4 << 3);
      bf16x8 afr[2];
#pragma unroll
      for (int mt = 0; mt < 2; ++mt) {
        int row = wave * 32 + mt * 16 + l15;
        int sw  = (row & 7) << 4;
        s16x8 t;
        t.lo = *(const s16x4*)(lAb + row * 128 + (ko ^ sw));
        t.hi = *(const s16x4*)(lAb + row * 128 + ((ko + 32) ^ sw));
        afr[mt] = __builtin_bit_cast(bf16x8, t);
      }
#pragma unroll
      for (int nt = 0; nt < 3; ++nt) {
        const int swx = (l15 & 7) << 4;
        const char* bp = lXb + nt * 2048 + l15 * 128;
        s16x8 t;
        t.lo = *(const s16x4*)(bp + (ko ^ swx));
        t.hi = *(const s16x4*)(bp + ((ko + 32) ^ swx));
        bf16x8 bfr = __builtin_bit_cast(bf16x8, t);
#pragma unroll
        for (int mt = 0; mt < 2; ++mt)
          acc[mt][nt] = __builtin_amdgcn_mfma_f32_16x16x32_bf16(afr[mt], bfr, acc[mt][nt], 0, 0, 0);
      }
    }
  }
#pragma unroll
  for (int mt = 0; mt < 2; ++mt)
#pragma unroll
    for (int nt = 0; nt < 3; ++nt) {
      int ch   = nt * 16 + l15;
      int row0 = mblk * 128 + wave * 32 + mt * 16 + (l4 << 2);
      s16x4 o;
      o.x = (short)f32_bf16(acc[mt][nt][0]); o.y = (short)f32_bf16(acc[mt][nt][1]);
      o.z = (short)f32_bf16(acc[mt][nt][2]); o.w = (short)f32_bf16(acc[mt][nt][3]);
      *(s16x4*)(Yb + (size_t)ch * NN + row0) = o;
    }
}

// ---------------------------------------------------------------------------
// gate_ru: r_u = sigmoid(h1 @ W_ru + b_ru); H2 slot0 = [inputs, r*states]; u out
// ---------------------------------------------------------------------------
__global__ __launch_bounds__(256)
void gate_ru_k(const unsigned short* __restrict__ H1,
               const float* __restrict__ W, const float* __restrict__ bias,
               const float* __restrict__ inputs, const float* __restrict__ states,
               unsigned short* __restrict__ H2, float* __restrict__ ubuf) {
  int gid = blockIdx.x * 256 + threadIdx.x;
  int b = gid >> 10, n = gid & 1023;
  const unsigned short* hb = H1 + (size_t)b * HB;
  float acc[64];
#pragma unroll
  for (int o = 0; o < 64; ++o) acc[o] = bias[o];
  for (int j = 0; j < 5; ++j) {
    const unsigned short* sb = hb + j * 3 * SUBT;
    for (int c = 0; c < 34; ++c) {
      float xv = bf16_f32(sb[(c >> 4) * SUBT + (c & 15) * NN + n]);
      const float* wr = W + (j * 34 + c) * 64;
#pragma unroll
      for (int o = 0; o < 64; ++o) acc[o] = fmaf(xv, wr[o], acc[o]);
    }
  }
  unsigned short* xb = H2 + (size_t)b * HB;
  xb[0 * NN + n] = f32_bf16(inputs[gid * 2 + 0]);
  xb[1 * NN + n] = f32_bf16(inputs[gid * 2 + 1]);
#pragma unroll
  for (int o = 0; o < 32; ++o) {
    float r = 1.f / (1.f + __expf(-acc[o]));
    float u = 1.f / (1.f + __expf(-acc[32 + o]));
    int ch = 2 + o;
    xb[(ch >> 4) * SUBT + (ch & 15) * NN + n] = f32_bf16(r * states[gid * 32 + o]);
    ubuf[((size_t)b * 32 + o) * NN + n] = u;
  }
#pragma unroll
  for (int ch = 34; ch < 48; ++ch)
    xb[2 * SUBT + (ch & 15) * NN + n] = 0;
}

// ---------------------------------------------------------------------------
// gate_c: c = tanh(h2 @ W_c + b_c); out = u*states + (1-u)*c (written twice)
// ---------------------------------------------------------------------------
__global__ __launch_bounds__(256)
void gate_c_k(const unsigned short* __restrict__ H2,
              const float* __restrict__ W, const float* __restrict__ bias,
              const float* __restrict__ states, const float* __restrict__ ubuf,
              float* __restrict__ out) {
  int gid = blockIdx.x * 256 + threadIdx.x;
  int b = gid >> 10, n = gid & 1023;
  const unsigned short* hb = H2 + (size_t)b * HB;
  float acc[32];
#pragma unroll
  for (int o = 0; o < 32; ++o) acc[o] = bias[o];
  for (int j = 0; j < 5; ++j) {
    const unsigned short* sb = hb + j * 3 * SUBT;
    for (int c = 0; c < 34; ++c) {
      float xv = bf16_f32(sb[(c >> 4) * SUBT + (c & 15) * NN + n]);
      const float* wr = W + (j * 34 + c) * 32;
#pragma unroll
      for (int o = 0; o < 32; ++o) acc[o] = fmaf(xv, wr[o], acc[o]);
    }
  }
  float res[32];
#pragma unroll
  for (int o = 0; o < 32; ++o) {
    float cc = tanhf(acc[o]);
    float u  = ubuf[((size_t)b * 32 + o) * NN + n];
    float sv = states[gid * 32 + o];
    res[o] = u * sv + (1.f - u) * cc;
  }
  float* o0 = out + (size_t)gid * 32;
#pragma unroll
  for (int q = 0; q < 8; ++q) {
    f32x4 v = { res[q * 4 + 0], res[q * 4 + 1], res[q * 4 + 2], res[q * 4 + 3] };
    *(f32x4*)(o0 + q * 4) = v;
    *(f32x4*)(o0 + OUTCOPY + q * 4) = v;
  }
}

// ---------------------------------------------------------------------------
extern "C" void kernel_launch(void* const* d_in, const int* in_sizes, int n_in,
                              void* d_out, int out_size, void* d_ws, size_t ws_size,
                              hipStream_t stream) {
  (void)in_sizes; (void)n_in; (void)out_size;
  const float* inputs   = (const float*)d_in[0];
  const float* supports = (const float*)d_in[1];
  const float* states   = (const float*)d_in[2];
  const float* W_ru     = (const float*)d_in[3];
  const float* b_ru     = (const float*)d_in[4];
  const float* W_c      = (const float*)d_in[5];
  const float* b_c      = (const float*)d_in[6];
  float* out = (float*)d_out;

  char* ws = (char*)d_ws;
  const size_t szA = 134217728;
  const size_t szH = 15728640;
  const size_t szU = 4194304;
  const bool pathA = ws_size >= szA + 2 * szH + szU;
  const size_t off = pathA ? szA : 0;

  unsigned short* Apk = (unsigned short*)ws;
  unsigned short* H1  = (unsigned short*)(ws + off);
  unsigned short* H2  = (unsigned short*)(ws + off + szH);
  float*          ub  = (float*)(ws + off + 2 * szH);

  dim3 vgrid(4, 32, 2), sgrid(8, 32, 2), blk256(256), blk512(512);

  if (pathA)
    cvt_pack<<<dim3(2048), blk256, 0, stream>>>(supports, Apk);

  pack_x1<<<dim3(128), blk256, 0, stream>>>(inputs, states, H1);

  if (pathA) {
    hop_v4<<<vgrid, blk512, 0, stream>>>(Apk, H1, H1, 0, 0, 1, 3);
    hop_v4<<<vgrid, blk512, 0, stream>>>(Apk, H1, H1, 1, 3, 2, 4);
  } else {
    hop_slow<<<sgrid, blk256, 0, stream>>>(supports, H1, H1, 0, 0, 1, 3);
    hop_slow<<<sgrid, blk256, 0, stream>>>(supports, H1, H1, 1, 3, 2, 4);
  }

  gate_ru_k<<<dim3(128), blk256, 0, stream>>>(H1, W_ru, b_ru, inputs, states, H2, ub);

  if (pathA) {
    hop_v4<<<vgrid, blk512, 0, stream>>>(Apk, H2, H2, 0, 0, 1, 3);
    hop_v4<<<vgrid, blk512, 0, stream>>>(Apk, H2, H2, 1, 3, 2, 4);
  } else {
    hop_slow<<<sgrid, blk256, 0, stream>>>(supports, H2, H2, 0, 0, 1, 3);
    hop_slow<<<sgrid, blk256, 0, stream>>>(supports, H2, H2, 1, 3, 2, 4);
  }

  gate_c_k<<<dim3(128), blk256, 0, stream>>>(H2, W_c, b_c, states, ub, out);
}